// Round 7
// baseline (297.843 us; speedup 1.0000x reference)
//
#include <hip/hip_runtime.h>

// Fused attention block for MI355X (gfx950).
// x[4096,768] fp32 -> QKV bf16 GEMM -> flash attention (12 heads, D=64) -> proj GEMM -> fp32 out.
// flash_attn v5: ALL pieces HW-validated (v3/round-5 passed with them):
//   32x32x16 MFMA layouts  A: m=lane&31,k=g*8+j ; B: n=lane&31,k=g*8+j ;
//   C/D: col=lane&31, row=(reg&3)+8*(reg>>2)+4*g  (g=lane>>5).
//   Wave owns 32 q-rows x ALL 4096 keys: no cross-wave reduction, no LDS, no barriers.
//   K/V^T frags straight from global (L2-resident, XCD swizzle); K prefetched one iter ahead
//   in-place; V issued a compute-phase early. P via lane^32 register exchange (v3-verbatim).
//   Un-normalized softmax (Q pre-scaled by 8*log2e), normalize once in epilogue.

typedef short bf16x8 __attribute__((ext_vector_type(8)));
typedef float f32x4 __attribute__((ext_vector_type(4)));
typedef float f32x16 __attribute__((ext_vector_type(16)));
typedef unsigned short u16;
typedef unsigned int u32;

__device__ __forceinline__ u16 f2bf(float f) {
  u32 u = __float_as_uint(f);
  u = (u + 0x7fffu + ((u >> 16) & 1u)) >> 16;  // RNE
  return (u16)u;
}

__device__ __forceinline__ u32 packbf(float a, float b) {  // RNE pair pack
  u32 ua = __float_as_uint(a), ub = __float_as_uint(b);
  ua += 0x7fffu + ((ua >> 16) & 1u);
  ub += 0x7fffu + ((ub >> 16) & 1u);
  return __builtin_amdgcn_perm(ub, ua, 0x07060302);
}

// hot-loop pack: round-half-up (<=0.5 ulp), 3 ops
__device__ __forceinline__ u32 packbf_hu(float a, float b) {
  return __builtin_amdgcn_perm(__float_as_uint(b) + 0x8000u,
                               __float_as_uint(a) + 0x8000u, 0x07060302);
}

__device__ __forceinline__ void gload16(const void* g, void* l) {
  __builtin_amdgcn_global_load_lds(
      (const __attribute__((address_space(1))) unsigned int*)g,
      (__attribute__((address_space(3))) unsigned int*)l, 16, 0, 0);
}

// ---------------- fused fp32 -> bf16 cast of x, qkv_w, proj_w ----------------
__global__ void cast3(const float* __restrict__ a, int na4,
                      const float* __restrict__ b, int nb4,
                      const float* __restrict__ c, int nc4,
                      u16* __restrict__ oa, u16* __restrict__ obp, u16* __restrict__ oc) {
  int i = blockIdx.x * blockDim.x + threadIdx.x;
  const float* src;
  u16* dst;
  int j = i;
  if (i < na4) { src = a; dst = oa; }
  else if (i < na4 + nb4) { src = b; dst = obp; j = i - na4; }
  else if (i < na4 + nb4 + nc4) { src = c; dst = oc; j = i - na4 - nb4; }
  else return;
  float4 v = ((const float4*)src)[j];
  ushort4 o;
  o.x = f2bf(v.x); o.y = f2bf(v.y); o.z = f2bf(v.z); o.w = f2bf(v.w);
  ((ushort4*)dst)[j] = o;
}

// ---------------- m97-style GEMM: C[M,N] = A[M,K] * B[N,K]^T + bias ----------------
// MODE 0: scatter bf16 into q/k/v. q,k: [H][4096][64] (q pre-scaled by 8*log2e); v: [H][64][4096].
// MODE 1: fp32 out[M,N] (final projection, N=768)
template <int MODE>
__global__ __launch_bounds__(256, 2) void gemm_bt(
    const u16* __restrict__ A, const u16* __restrict__ B,
    const float* __restrict__ bias,
    u16* __restrict__ qb, u16* __restrict__ kbuf, u16* __restrict__ vb,
    float* __restrict__ outp, int K, int N) {
  __shared__ __align__(16) u16 As[128 * 32];
  __shared__ __align__(16) u16 Bs[128 * 32];
  const int tid = threadIdx.x, lane = tid & 63, w = tid >> 6;
  const int wr = w >> 1, wc = w & 1, quad = lane >> 4, l15 = lane & 15;
  const int m0 = blockIdx.y * 128, n0 = blockIdx.x * 128;

  f32x4 acc[4][4];
#pragma unroll
  for (int i = 0; i < 4; ++i)
#pragma unroll
    for (int j = 0; j < 4; ++j) acc[i][j] = (f32x4){0.f, 0.f, 0.f, 0.f};

  for (int k0 = 0; k0 < K; k0 += 32) {
    __syncthreads();
#pragma unroll
    for (int i = 0; i < 2; ++i) {
      int chunk = i * 256 + w * 64 + lane;
      int row = chunk >> 2, kc = chunk & 3;
      gload16(A + (size_t)(m0 + row) * K + k0 + kc * 8, (char*)As + chunk * 16);
      gload16(B + (size_t)(n0 + row) * K + k0 + kc * 8, (char*)Bs + chunk * 16);
    }
    __syncthreads();
    bf16x8 af[4], bfr[4];
#pragma unroll
    for (int mi = 0; mi < 4; ++mi)
      af[mi] = *(const bf16x8*)&As[(wr * 64 + mi * 16 + l15) * 32 + quad * 8];
#pragma unroll
    for (int ni = 0; ni < 4; ++ni)
      bfr[ni] = *(const bf16x8*)&Bs[(wc * 64 + ni * 16 + l15) * 32 + quad * 8];
#pragma unroll
    for (int mi = 0; mi < 4; ++mi)
#pragma unroll
      for (int ni = 0; ni < 4; ++ni)
        acc[mi][ni] = __builtin_amdgcn_mfma_f32_16x16x32_bf16(af[mi], bfr[ni], acc[mi][ni], 0, 0, 0);
  }

#pragma unroll
  for (int mi = 0; mi < 4; ++mi) {
    int row = m0 + wr * 64 + mi * 16 + quad * 4;
#pragma unroll
    for (int ni = 0; ni < 4; ++ni) {
      int col = n0 + wc * 64 + ni * 16 + l15;
      float bv = bias[col];
      if (MODE == 0) {
        int t = col / 768;
        int rem = col - t * 768;
        int hh = rem >> 6, d = rem & 63;
        if (t == 2) {
          u16* dst = vb + (size_t)hh * 64 * 4096 + (size_t)d * 4096 + row;
          ushort4 pk;
          pk.x = f2bf(acc[mi][ni][0] + bv);
          pk.y = f2bf(acc[mi][ni][1] + bv);
          pk.z = f2bf(acc[mi][ni][2] + bv);
          pk.w = f2bf(acc[mi][ni][3] + bv);
          *(ushort4*)dst = pk;
        } else {
          u16* dst = (t == 0 ? qb : kbuf) + (size_t)hh * 4096 * 64 + d;
          float sc = (t == 0) ? 11.541560327111707f : 1.f;  // 8*log2(e)
#pragma unroll
          for (int r = 0; r < 4; ++r)
            dst[(size_t)(row + r) * 64] = f2bf((acc[mi][ni][r] + bv) * sc);
        }
      } else {
#pragma unroll
        for (int r = 0; r < 4; ++r)
          outp[(size_t)(row + r) * N + col] = acc[mi][ni][r] + bv;
      }
    }
  }
}

// ---------------- flash attention v5: wave = 32 q x all keys, no LDS ----------------
__global__ __launch_bounds__(128, 2) void flash_attn(
    const u16* __restrict__ qb, const u16* __restrict__ kb,
    const u16* __restrict__ vtg, u16* __restrict__ ob) {
  const int b = blockIdx.x;
  const int gg = (b & 7) * 96 + (b >> 3);   // XCD swizzle: 1.5 heads per XCD (K/V in its L2)
  const int h = gg >> 6;
  const int q0 = (gg & 63) * 64;

  const int tid = threadIdx.x, lane = tid & 63, w = tid >> 6;  // w in {0,1}
  const int col = lane & 31, g = lane >> 5;
  const u16* qh = qb + (size_t)h * 4096 * 64;
  const u16* kh = kb + (size_t)h * 4096 * 64;
  const u16* vh = vtg + (size_t)h * 64 * 4096;  // [d][key]

  // Q B-frags (loop-invariant): n = q0 + w*32 + col, k = kd*16 + g*8 + j
  bf16x8 qf[4];
#pragma unroll
  for (int kd = 0; kd < 4; ++kd)
    qf[kd] = *(const bf16x8*)&qh[(size_t)(q0 + w * 32 + col) * 64 + kd * 16 + g * 8];

  f32x16 oacc[2];  // [d-tile]: O[q][d], C-layout rows=q, col=d
#pragma unroll
  for (int i = 0; i < 2; ++i)
#pragma unroll
    for (int r = 0; r < 16; ++r) oacc[i][r] = 0.f;
  float lsum = 0.f;  // per q=col, this g-half's keys (xor32 at end)

  // K A-frag base: row = key = kt + mt*32 + col, d-off = kd*16 + g*8
  const u16* kwp = kh + (size_t)col * 64 + g * 8;
  bf16x8 kc[2][4];
#pragma unroll
  for (int mt = 0; mt < 2; ++mt)
#pragma unroll
    for (int kd = 0; kd < 4; ++kd)
      kc[mt][kd] = *(const bf16x8*)(kwp + mt * 2048 + kd * 16);

  for (int t = 0; t < 64; ++t) {
    const size_t kt = (size_t)t * 64;

    // V^T B-frags (d = dt*32+col, keys kt + ks*16 + g*8); issued early, used at iter end
    bf16x8 vf[2][4];
#pragma unroll
    for (int dt = 0; dt < 2; ++dt)
#pragma unroll
      for (int ks = 0; ks < 4; ++ks)
        vf[dt][ks] = *(const bf16x8*)&vh[(size_t)(dt * 32 + col) * 4096 + kt + ks * 16 + g * 8];

    // S^T per 32-key m-tile -> exp -> pack; K prefetch in-place for t+1
    u32 pd[2][8];
#pragma unroll
    for (int mt = 0; mt < 2; ++mt) {
      f32x16 s;
#pragma unroll
      for (int r = 0; r < 16; ++r) s[r] = 0.f;
#pragma unroll
      for (int kd = 0; kd < 4; ++kd)
        s = __builtin_amdgcn_mfma_f32_32x32x16_bf16(kc[mt][kd], qf[kd], s, 0, 0, 0);
      if (t < 63) {
        const u16* knp = kwp + (size_t)(t + 1) * 4096 + mt * 2048;
#pragma unroll
        for (int kd = 0; kd < 4; ++kd)
          kc[mt][kd] = *(const bf16x8*)(knp + kd * 16);
      }
#pragma unroll
      for (int j = 0; j < 8; ++j) {
        float pa = exp2f(s[2 * j]);
        float pb = exp2f(s[2 * j + 1]);
        lsum += pa + pb;
        pd[mt][j] = packbf_hu(pa, pb);
      }
    }

    // PV: A = P via lane^32 exchange (v3-verbatim), B = V^T frags
#pragma unroll
    for (int ks = 0; ks < 4; ++ks) {
      const u32* arr = pd[ks >> 1];
      const int i0 = (ks & 1) * 4;
      u32 a0 = arr[i0], a1 = arr[i0 + 1], a2 = arr[i0 + 2], a3 = arr[i0 + 3];
      u32 s1 = (u32)__shfl_xor((int)(g ? a0 : a2), 32);
      u32 s2 = (u32)__shfl_xor((int)(g ? a1 : a3), 32);
      uint4 ad;
      ad.x = g ? s1 : a0;
      ad.y = g ? s2 : a1;
      ad.z = g ? a2 : s1;
      ad.w = g ? a3 : s2;
      bf16x8 pf = __builtin_bit_cast(bf16x8, ad);
      oacc[0] = __builtin_amdgcn_mfma_f32_32x32x16_bf16(pf, vf[0][ks], oacc[0], 0, 0, 0);
      oacc[1] = __builtin_amdgcn_mfma_f32_32x32x16_bf16(pf, vf[1][ks], oacc[1], 0, 0, 0);
    }
  }

  // epilogue: normalize (lsum shared across g via xor32), store bf16 [4096][768]
  lsum += __shfl_xor(lsum, 32);
  float linv = 1.f / lsum;  // valid for q = col on every lane
  u16* aout = ob + (size_t)(q0 + w * 32) * 768 + h * 64;
#pragma unroll
  for (int r = 0; r < 16; ++r) {
    int q = (r & 3) + 8 * (r >> 2) + 4 * g;
    float lr = __shfl(linv, q);  // lane q holds linv for q-row q
#pragma unroll
    for (int dt = 0; dt < 2; ++dt)
      aout[(size_t)q * 768 + dt * 32 + col] = f2bf(oacc[dt][r] * lr);
  }
}

extern "C" void kernel_launch(void* const* d_in, const int* in_sizes, int n_in,
                              void* d_out, int out_size, void* d_ws, size_t ws_size,
                              hipStream_t stream) {
  const float* x      = (const float*)d_in[0];
  const float* qkv_w  = (const float*)d_in[1];
  const float* qkv_b  = (const float*)d_in[2];
  const float* proj_w = (const float*)d_in[3];
  const float* proj_b = (const float*)d_in[4];
  float* out = (float*)d_out;

  const int N = 4096, C = 768, H = 12, D = 64, C3 = 2304;
  char* ws = (char*)d_ws;
  size_t off = 0;
  u16* xb    = (u16*)(ws + off); off += (size_t)N * C * 2;
  u16* wqkv  = (u16*)(ws + off); off += (size_t)C3 * C * 2;
  u16* wproj = (u16*)(ws + off); off += (size_t)C * C * 2;
  u16* qbuf  = (u16*)(ws + off); off += (size_t)H * N * D * 2;
  u16* kbuf  = (u16*)(ws + off); off += (size_t)H * N * D * 2;
  u16* vbuf  = (u16*)(ws + off); off += (size_t)H * N * D * 2;  // V^T [H][64][4096]
  u16* aob = xb;  // xb dead after QKV GEMM

  const int na4 = N * C / 4, nb4 = C3 * C / 4, nc4 = C * C / 4;
  int ntot = na4 + nb4 + nc4;
  cast3<<<(ntot + 255) / 256, 256, 0, stream>>>(x, na4, qkv_w, nb4, proj_w, nc4, xb, wqkv, wproj);

  dim3 g1(C3 / 128, N / 128);
  gemm_bt<0><<<g1, 256, 0, stream>>>(xb, wqkv, qkv_b, qbuf, kbuf, vbuf, nullptr, C, C3);

  flash_attn<<<768, 128, 0, stream>>>(qbuf, kbuf, vbuf, aob);

  dim3 g3(C / 128, N / 128);
  gemm_bt<1><<<g3, 256, 0, stream>>>(aob, wproj, proj_b, nullptr, nullptr, nullptr, out, C, C);
}